// Round 7
// baseline (158.606 us; speedup 1.0000x reference)
//
#include <hip/hip_runtime.h>

#define NB 4
#define C 64
#define H 256
#define W 256
#define HW (H * W)
#define NH 10
#define KK 5
#define NBINS 1024
#define CHUNK 256
#define NCHUNK (HW / CHUNK)

// ---- fused speculative hash (grid = NB*NCHUNK = 1024 blocks) ----
// Per (batch, chunk of 256 px): sumsq partial, LSH code, sigmoid(conv proj),
// per-chunk histogram. Computed for ALL batches; downstream selects best.
// rv/cw read with wave-uniform indices -> scalar loads, no LDS pipe pressure.
__global__ __launch_bounds__(256) void spec_hash_kernel(const float* __restrict__ Xall,
                                                        const float* __restrict__ rvecs,
                                                        const float* __restrict__ cwg,
                                                        float* __restrict__ part,
                                                        float* __restrict__ filtU,
                                                        int* __restrict__ dec,
                                                        int* __restrict__ hist) {
    __shared__ int lhist[NBINS];
    __shared__ float red[256];
    int t = threadIdx.x;
    int b = blockIdx.x >> 8;
    int ch = blockIdx.x & (NCHUNK - 1);
    int p0 = ch * CHUNK;
    for (int i = t; i < NBINS; i += 256) lhist[i] = 0;

    const float* X = Xall + (size_t)b * C * HW + p0 + t;
    float acc[NH], cacc[NH];
#pragma unroll
    for (int h = 0; h < NH; h++) { acc[h] = 0.f; cacc[h] = 0.f; }
    float ssq = 0.f;
#pragma unroll 8
    for (int i = 0; i < C; i++) {
        float v = X[(size_t)i * HW];
        ssq += v * v;
#pragma unroll
        for (int h = 0; h < NH; h++) {
            acc[h] += v * rvecs[h * C + i];
            cacc[h] += v * cwg[h * C + i];
        }
    }
    int d = 0;
#pragma unroll
    for (int h = 0; h < NH; h++) d |= (acc[h] > 0.f) ? (1 << h) : 0;
    dec[(size_t)b * HW + p0 + t] = d;

    float* fu = filtU + ((size_t)b * HW + p0 + t) * 12;
    float sg[NH];
#pragma unroll
    for (int h = 0; h < NH; h++) sg[h] = 1.f / (1.f + expf(-cacc[h]));
    *reinterpret_cast<float4*>(fu + 0) = make_float4(sg[0], sg[1], sg[2], sg[3]);
    *reinterpret_cast<float4*>(fu + 4) = make_float4(sg[4], sg[5], sg[6], sg[7]);
    *reinterpret_cast<float4*>(fu + 8) = make_float4(sg[8], sg[9], 0.f, 0.f);

    __syncthreads();  // lhist zeroed
    atomicAdd(&lhist[d], 1);
    red[t] = ssq;
    __syncthreads();  // atomics + red landed
    for (int off = 128; off; off >>= 1) {
        if (t < off) red[t] += red[t + off];
        __syncthreads();
    }
    if (t == 0) part[blockIdx.x] = red[0];  // part[b*NCHUNK + ch]
    for (int i = t; i < NBINS; i += 256)
        hist[((size_t)b * NBINS + i) * NCHUNK + ch] = lhist[i];
}

// ---- per-bin chunk scan on the BEST batch's hist (one bin per wave) ----
__global__ __launch_bounds__(256) void scan1_kernel(const float* __restrict__ part,
                                                    int* __restrict__ hist,
                                                    int* __restrict__ bintot) {
    __shared__ float4 red4[256];
    int t = threadIdx.x;
    // redundant argmax over part[NB][NCHUNK]
    float4 ss;
    ss.x = part[0 * NCHUNK + t];
    ss.y = part[1 * NCHUNK + t];
    ss.z = part[2 * NCHUNK + t];
    ss.w = part[3 * NCHUNK + t];
    red4[t] = ss;
    __syncthreads();
    for (int off = 128; off; off >>= 1) {
        if (t < off) {
            red4[t].x += red4[t + off].x;
            red4[t].y += red4[t + off].y;
            red4[t].z += red4[t + off].z;
            red4[t].w += red4[t + off].w;
        }
        __syncthreads();
    }
    float4 nm = red4[0];
    float nv[NB] = {nm.x, nm.y, nm.z, nm.w};
    int best = 0;
    float m = nv[0];
#pragma unroll
    for (int i = 1; i < NB; i++)
        if (nv[i] > m) { m = nv[i]; best = i; }

    int lane = t & 63;
    int bin = blockIdx.x * 4 + (t >> 6);
    int* base = hist + ((size_t)best * NBINS + bin) * NCHUNK;
    int4 v = *reinterpret_cast<int4*>(base + lane * 4);
    int s0 = v.x, s1 = s0 + v.y, s2 = s1 + v.z, s3 = s2 + v.w;
    int s = s3;
#pragma unroll
    for (int off = 1; off < 64; off <<= 1) {
        int nbr = __shfl_up(s, off);
        if (lane >= off) s += nbr;
    }
    int excl = s - s3;
    int4 o;
    o.x = excl;
    o.y = excl + s0;
    o.z = excl + s1;
    o.w = excl + s2;
    *reinterpret_cast<int4*>(base + lane * 4) = o;
    if (lane == 63) bintot[bin] = s;
}

// ---- stable scatter: filt written directly at sorted position ----
__global__ __launch_bounds__(256) void scatter_kernel(const float* __restrict__ part,
                                                      const int* __restrict__ dec,
                                                      const int* __restrict__ hist,
                                                      const int* __restrict__ bintot,
                                                      const float* __restrict__ filtU,
                                                      float* __restrict__ filt) {
    __shared__ float4 red4[256];
    __shared__ int boffs[NBINS];
    __shared__ int wtot[4];
    __shared__ int keys[CHUNK];
    int t = threadIdx.x;
    // redundant argmax
    float4 ss;
    ss.x = part[0 * NCHUNK + t];
    ss.y = part[1 * NCHUNK + t];
    ss.z = part[2 * NCHUNK + t];
    ss.w = part[3 * NCHUNK + t];
    red4[t] = ss;
    __syncthreads();
    for (int off = 128; off; off >>= 1) {
        if (t < off) {
            red4[t].x += red4[t + off].x;
            red4[t].y += red4[t + off].y;
            red4[t].z += red4[t + off].z;
            red4[t].w += red4[t + off].w;
        }
        __syncthreads();
    }
    float4 nm = red4[0];
    float nv[NB] = {nm.x, nm.y, nm.z, nm.w};
    int best = 0;
    float m = nv[0];
#pragma unroll
    for (int i = 1; i < NB; i++)
        if (nv[i] > m) { m = nv[i]; best = i; }

    // exclusive scan of bintot -> boffs
    int lane = t & 63;
    int w = t >> 6;
    int4 v = *reinterpret_cast<const int4*>(bintot + t * 4);
    int s0 = v.x, s1 = s0 + v.y, s2 = s1 + v.z, s3 = s2 + v.w;
    int s = s3;
#pragma unroll
    for (int off = 1; off < 64; off <<= 1) {
        int nbr = __shfl_up(s, off);
        if (lane >= off) s += nbr;
    }
    int excl = s - s3;
    if (lane == 63) wtot[w] = s;
    __syncthreads();
    int wbase = 0;
#pragma unroll
    for (int i = 0; i < 4; i++) wbase += (i < w) ? wtot[i] : 0;
    boffs[t * 4 + 0] = wbase + excl;
    boffs[t * 4 + 1] = wbase + excl + s0;
    boffs[t * 4 + 2] = wbase + excl + s1;
    boffs[t * 4 + 3] = wbase + excl + s2;

    int p0 = blockIdx.x * CHUNK;
    int k = dec[(size_t)best * HW + p0 + t];
    keys[t] = k;
    __syncthreads();
    int r = 0;
    for (int j = 0; j < t; j++) r += (keys[j] == k) ? 1 : 0;
    int dst = boffs[k] + hist[((size_t)best * NBINS + k) * NCHUNK + blockIdx.x] + r;

    const float4* fu = reinterpret_cast<const float4*>(filtU + ((size_t)best * HW + p0 + t) * 12);
    float4 a = fu[0], b4 = fu[1], c4 = fu[2];
    float vv[10] = {a.x, a.y, a.z, a.w, b4.x, b4.y, b4.z, b4.w, c4.x, c4.y};
#pragma unroll
    for (int h = 0; h < NH; h++) filt[(size_t)h * HW + dst] = vv[h];
}

// ---- horizontal strip conv (float4) ----
__global__ __launch_bounds__(256) void convh_kernel(const float* __restrict__ X,
                                                    const float* __restrict__ filt,
                                                    float* __restrict__ out1) {
    int bid = blockIdx.x;
    int rb = bid & 63;
    int c = (bid >> 6) & (C - 1);
    int n = bid >> 12;
    int g = c >> 5;
    int t = threadIdx.x;
    int x4 = (t & 63) * 4;
    int y = rb * 4 + (t >> 6);

    const float* src = X + (((size_t)n * C + c) * H + y) * W;
    float4 M = *reinterpret_cast<const float4*>(src + x4);
    float s0, s1, s6, s7;
    if (x4 > 0) {
        float4 L = *reinterpret_cast<const float4*>(src + x4 - 4);
        s0 = L.z; s1 = L.w;
    } else {
        s0 = M.z; s1 = M.y;
    }
    if (x4 < W - 4) {
        float4 R = *reinterpret_cast<const float4*>(src + x4 + 4);
        s6 = R.x; s7 = R.y;
    } else {
        s6 = M.z; s7 = M.y;
    }
    float s[8] = {s0, s1, M.x, M.y, M.z, M.w, s6, s7};

    const float* fb = filt + (size_t)g * KK * HW + (size_t)y * W + x4;
    float4 acc = make_float4(0.f, 0.f, 0.f, 0.f);
#pragma unroll
    for (int k = 0; k < KK; k++) {
        float4 f = *reinterpret_cast<const float4*>(fb + (size_t)k * HW);
        acc.x += s[k] * f.x;
        acc.y += s[k + 1] * f.y;
        acc.z += s[k + 2] * f.z;
        acc.w += s[k + 3] * f.w;
    }
    *reinterpret_cast<float4*>(out1 + (((size_t)n * C + c) * H + y) * W + x4) = acc;
}

// ---- vertical strip conv (float4 sliding window, TY=16) + affine ----
__global__ __launch_bounds__(256) void convv_kernel(const float* __restrict__ out1,
                                                    const float* __restrict__ filt,
                                                    const float* __restrict__ x,
                                                    const float* __restrict__ gamma,
                                                    const float* __restrict__ beta,
                                                    float* __restrict__ out) {
    int bid = blockIdx.x;
    int yc = bid & 3;
    int c = (bid >> 2) & (C - 1);
    int n = bid >> 8;
    int g = c >> 5;
    int t = threadIdx.x;
    int x4 = (t & 63) * 4;
    int ys = yc * 64 + (t >> 6) * 16;

    const float* plane = out1 + ((size_t)n * C + c) * HW;
    float4 win[KK];
#pragma unroll
    for (int i = 0; i < 4; i++) {
        int yy = ys - 2 + i;
        yy = yy < 0 ? -yy : yy;
        win[i] = *reinterpret_cast<const float4*>(plane + (size_t)yy * W + x4);
    }
    float gm = gamma[c], bt = beta[c];
    const float* fgb = filt + (size_t)g * KK * HW;
    for (int dy = 0; dy < 16; dy++) {
        int y = ys + dy;
        int yy = y + 2;
        yy = (yy >= H) ? (2 * H - 2 - yy) : yy;
        win[4] = *reinterpret_cast<const float4*>(plane + (size_t)yy * W + x4);
        const float* fb = fgb + (size_t)y * W + x4;
        float4 acc = make_float4(0.f, 0.f, 0.f, 0.f);
#pragma unroll
        for (int k = 0; k < KK; k++) {
            float4 f = *reinterpret_cast<const float4*>(fb + (size_t)k * HW);
            acc.x += win[k].x * f.x;
            acc.y += win[k].y * f.y;
            acc.z += win[k].z * f.z;
            acc.w += win[k].w * f.w;
        }
        size_t idx = (((size_t)n * C + c) * H + y) * W + x4;
        float4 xv = *reinterpret_cast<const float4*>(x + idx);
        float4 o;
        o.x = gm * acc.x + bt * xv.x;
        o.y = gm * acc.y + bt * xv.y;
        o.z = gm * acc.z + bt * xv.z;
        o.w = gm * acc.w + bt * xv.w;
        *reinterpret_cast<float4*>(out + idx) = o;
#pragma unroll
        for (int k = 0; k < 4; k++) win[k] = win[k + 1];
    }
}

extern "C" void kernel_launch(void* const* d_in, const int* in_sizes, int n_in,
                              void* d_out, int out_size, void* d_ws, size_t ws_size,
                              hipStream_t stream) {
    const float* x      = (const float*)d_in[0];
    const float* conv_h = (const float*)d_in[1];
    const float* conv_w = (const float*)d_in[2];
    const float* rv_h   = (const float*)d_in[3];
    const float* rv_w   = (const float*)d_in[4];
    const float* gamma  = (const float*)d_in[5];
    const float* beta   = (const float*)d_in[6];
    float* out = (float*)d_out;

    char* w = (char*)d_ws;
    size_t off = 0;
    float* out1   = (float*)(w + off); off += (size_t)NB * C * HW * 4;   // 67 MB
    float* filtU  = (float*)(w + off); off += (size_t)NB * HW * 12 * 4;  // 12.6 MB
    float* filt   = (float*)(w + off); off += (size_t)NH * HW * 4;       // 2.6 MB
    int*   dec    = (int*)  (w + off); off += (size_t)NB * HW * 4;       // 1 MB
    int*   hist   = (int*)  (w + off); off += (size_t)NB * NBINS * NCHUNK * 4;  // 4 MB
    int*   bintot = (int*)  (w + off); off += 4096;
    float* part1  = (float*)(w + off); off += (size_t)NB * NCHUNK * 4;
    float* part2  = (float*)(w + off); off += (size_t)NB * NCHUNK * 4;

    // ---------------- pass 1: horizontal ----------------
    spec_hash_kernel<<<NB * NCHUNK, 256, 0, stream>>>(x, rv_h, conv_h, part1, filtU, dec, hist);
    scan1_kernel<<<NBINS / 4, 256, 0, stream>>>(part1, hist, bintot);
    scatter_kernel<<<NCHUNK, 256, 0, stream>>>(part1, dec, hist, bintot, filtU, filt);
    convh_kernel<<<NB * C * (H / 4), 256, 0, stream>>>(x, filt, out1);

    // ---------------- pass 2: vertical + affine ----------------
    spec_hash_kernel<<<NB * NCHUNK, 256, 0, stream>>>(out1, rv_w, conv_w, part2, filtU, dec, hist);
    scan1_kernel<<<NBINS / 4, 256, 0, stream>>>(part2, hist, bintot);
    scatter_kernel<<<NCHUNK, 256, 0, stream>>>(part2, dec, hist, bintot, filtU, filt);
    convv_kernel<<<NB * C * 4, 256, 0, stream>>>(out1, filt, x, gamma, beta, out);
}

// Round 8
// 145.554 us; speedup vs baseline: 1.0897x; 1.0897x over previous
//
#include <hip/hip_runtime.h>

#define NB 4
#define C 64
#define H 256
#define W 256
#define HW (H * W)
#define NH 10
#define KK 5
#define NBINS 1024
#define CHUNK 256
#define NCHUNK (HW / CHUNK)

// ---------------- per-batch sum of squares (256 partials per batch) ----------------
__global__ __launch_bounds__(256) void sumsq_kernel(const float* __restrict__ x,
                                                    float* __restrict__ part) {
    int bid = blockIdx.x;
    int b = bid >> 8, ch = bid & 255;
    const float4* p = reinterpret_cast<const float4*>(x + (size_t)b * C * HW) + (size_t)ch * 4096;
    float s = 0.f;
    for (int i = threadIdx.x; i < 4096; i += 256) {
        float4 v = p[i];
        s += v.x * v.x + v.y * v.y + v.z * v.z + v.w * v.w;
    }
    __shared__ float red[256];
    red[threadIdx.x] = s;
    __syncthreads();
    for (int off = 128; off; off >>= 1) {
        if (threadIdx.x < off) red[threadIdx.x] += red[threadIdx.x + off];
        __syncthreads();
    }
    if (threadIdx.x == 0) part[bid] = red[0];
}

// ---------------- best-batch hash: float4 row loads + LDS transpose ----------------
// grid = NCHUNK. Fused redundant argmax over part[NB][per_batch].
// Outputs: dec, filtU (sigmoid'd conv projections), hist bin-major.
__global__ __launch_bounds__(256) void hash_kernel(const float* __restrict__ Xall,
                                                   const float* __restrict__ part,
                                                   int per_batch,
                                                   const float* __restrict__ rvecs,
                                                   const float* __restrict__ cwg,
                                                   float* __restrict__ filtU,
                                                   int* __restrict__ dec,
                                                   int* __restrict__ hist) {
    __shared__ float tile[32][CHUNK + 4];
    __shared__ float rv[NH * C];
    __shared__ float cw[NH * C];
    __shared__ int lhist[NBINS];
    __shared__ float4 red4[256];
    int t = threadIdx.x;
    for (int i = t; i < NH * C; i += 256) { rv[i] = rvecs[i]; cw[i] = cwg[i]; }
    for (int i = t; i < NBINS; i += 256) lhist[i] = 0;

    // redundant per-block argmax over batch norms (float4 partial reads)
    float4 ss = make_float4(0.f, 0.f, 0.f, 0.f);
    int q4 = per_batch >> 2;
    for (int i = t; i < q4; i += 256) {
        float4 a = *reinterpret_cast<const float4*>(part + 0 * per_batch + i * 4);
        float4 b = *reinterpret_cast<const float4*>(part + 1 * per_batch + i * 4);
        float4 c = *reinterpret_cast<const float4*>(part + 2 * per_batch + i * 4);
        float4 d = *reinterpret_cast<const float4*>(part + 3 * per_batch + i * 4);
        ss.x += a.x + a.y + a.z + a.w;
        ss.y += b.x + b.y + b.z + b.w;
        ss.z += c.x + c.y + c.z + c.w;
        ss.w += d.x + d.y + d.z + d.w;
    }
    red4[t] = ss;
    __syncthreads();
    for (int off = 128; off; off >>= 1) {
        if (t < off) {
            red4[t].x += red4[t + off].x;
            red4[t].y += red4[t + off].y;
            red4[t].z += red4[t + off].z;
            red4[t].w += red4[t + off].w;
        }
        __syncthreads();
    }
    float4 nm = red4[0];
    float nv[NB] = {nm.x, nm.y, nm.z, nm.w};
    int best = 0;
    float m = nv[0];
#pragma unroll
    for (int i = 1; i < NB; i++)
        if (nv[i] > m) { m = nv[i]; best = i; }

    const float* X = Xall + (size_t)best * C * HW;
    int p0 = blockIdx.x * CHUNK;
    int lane = t & 63, cq = t >> 6;
    float acc[NH], cacc[NH];
#pragma unroll
    for (int h = 0; h < NH; h++) { acc[h] = 0.f; cacc[h] = 0.f; }

    for (int half = 0; half < 2; half++) {
        __syncthreads();  // tile reuse barrier
        const float* Xh = X + (size_t)(half * 32) * HW + p0;
#pragma unroll
        for (int rep = 0; rep < 8; rep++) {
            int cl = rep * 4 + cq;
            float4 v = *reinterpret_cast<const float4*>(Xh + (size_t)cl * HW + lane * 4);
            *reinterpret_cast<float4*>(&tile[cl][lane * 4]) = v;
        }
        __syncthreads();
#pragma unroll
        for (int c = 0; c < 32; c++) {
            float v = tile[c][t];
            int ci = half * 32 + c;
#pragma unroll
            for (int h = 0; h < NH; h++) {
                acc[h] += v * rv[h * C + ci];
                cacc[h] += v * cw[h * C + ci];
            }
        }
    }
    int d = 0;
#pragma unroll
    for (int h = 0; h < NH; h++) d |= (acc[h] > 0.f) ? (1 << h) : 0;
    dec[p0 + t] = d;
    atomicAdd(&lhist[d], 1);

    float sg[NH];
#pragma unroll
    for (int h = 0; h < NH; h++) sg[h] = 1.f / (1.f + expf(-cacc[h]));
    float* fu = filtU + (size_t)(p0 + t) * 12;
    *reinterpret_cast<float4*>(fu + 0) = make_float4(sg[0], sg[1], sg[2], sg[3]);
    *reinterpret_cast<float4*>(fu + 4) = make_float4(sg[4], sg[5], sg[6], sg[7]);
    *reinterpret_cast<float4*>(fu + 8) = make_float4(sg[8], sg[9], 0.f, 0.f);

    __syncthreads();
    for (int i = t; i < NBINS; i += 256) hist[(size_t)i * NCHUNK + blockIdx.x] = lhist[i];
}

// ---------------- parallel per-bin chunk scan: one bin per wave ----------------
__global__ __launch_bounds__(256) void scan1_kernel(int* __restrict__ hist,
                                                    int* __restrict__ bintot) {
    int t = threadIdx.x;
    int lane = t & 63;
    int b = blockIdx.x * 4 + (t >> 6);
    int4 v = *reinterpret_cast<int4*>(hist + (size_t)b * NCHUNK + lane * 4);
    int s0 = v.x, s1 = s0 + v.y, s2 = s1 + v.z, s3 = s2 + v.w;
    int s = s3;
#pragma unroll
    for (int off = 1; off < 64; off <<= 1) {
        int nbr = __shfl_up(s, off);
        if (lane >= off) s += nbr;
    }
    int excl = s - s3;
    int4 o;
    o.x = excl;
    o.y = excl + s0;
    o.z = excl + s1;
    o.w = excl + s2;
    *reinterpret_cast<int4*>(hist + (size_t)b * NCHUNK + lane * 4) = o;
    if (lane == 63) bintot[b] = s;
}

// ---------------- stable scatter: filt written directly at sorted position ----------------
__global__ __launch_bounds__(256) void scatter_kernel(const int* __restrict__ dec,
                                                      const int* __restrict__ hist,
                                                      const int* __restrict__ bintot,
                                                      const float* __restrict__ filtU,
                                                      float* __restrict__ filt) {
    __shared__ int boffs[NBINS];
    __shared__ int wtot[4];
    __shared__ int keys[CHUNK];
    int t = threadIdx.x;
    int lane = t & 63;
    int w = t >> 6;
    int4 v = *reinterpret_cast<const int4*>(bintot + t * 4);
    int s0 = v.x, s1 = s0 + v.y, s2 = s1 + v.z, s3 = s2 + v.w;
    int s = s3;
#pragma unroll
    for (int off = 1; off < 64; off <<= 1) {
        int nbr = __shfl_up(s, off);
        if (lane >= off) s += nbr;
    }
    int excl = s - s3;
    if (lane == 63) wtot[w] = s;
    __syncthreads();
    int wbase = 0;
#pragma unroll
    for (int i = 0; i < 4; i++) wbase += (i < w) ? wtot[i] : 0;
    boffs[t * 4 + 0] = wbase + excl;
    boffs[t * 4 + 1] = wbase + excl + s0;
    boffs[t * 4 + 2] = wbase + excl + s1;
    boffs[t * 4 + 3] = wbase + excl + s2;

    int p0 = blockIdx.x * CHUNK;
    int k = dec[p0 + t];
    keys[t] = k;
    __syncthreads();
    int r = 0;
    for (int j = 0; j < t; j++) r += (keys[j] == k) ? 1 : 0;
    int dst = boffs[k] + hist[(size_t)k * NCHUNK + blockIdx.x] + r;

    const float4* fu = reinterpret_cast<const float4*>(filtU + (size_t)(p0 + t) * 12);
    float4 a = fu[0], b4 = fu[1], c4 = fu[2];
    float vv[10] = {a.x, a.y, a.z, a.w, b4.x, b4.y, b4.z, b4.w, c4.x, c4.y};
#pragma unroll
    for (int h = 0; h < NH; h++) filt[(size_t)h * HW + dst] = vv[h];
}

// ---------------- horizontal strip conv (float4) + sumsq partials ----------------
__global__ __launch_bounds__(256) void convh_kernel(const float* __restrict__ X,
                                                    const float* __restrict__ filt,
                                                    float* __restrict__ out1,
                                                    float* __restrict__ part) {
    int bid = blockIdx.x;
    int rb = bid & 63;
    int c = (bid >> 6) & (C - 1);
    int n = bid >> 12;
    int g = c >> 5;
    int t = threadIdx.x;
    int x4 = (t & 63) * 4;
    int y = rb * 4 + (t >> 6);

    const float* src = X + (((size_t)n * C + c) * H + y) * W;
    float4 M = *reinterpret_cast<const float4*>(src + x4);
    float s0, s1, s6, s7;
    if (x4 > 0) {
        float4 L = *reinterpret_cast<const float4*>(src + x4 - 4);
        s0 = L.z; s1 = L.w;
    } else {
        s0 = M.z; s1 = M.y;
    }
    if (x4 < W - 4) {
        float4 R = *reinterpret_cast<const float4*>(src + x4 + 4);
        s6 = R.x; s7 = R.y;
    } else {
        s6 = M.z; s7 = M.y;
    }
    float s[8] = {s0, s1, M.x, M.y, M.z, M.w, s6, s7};

    const float* fb = filt + (size_t)g * KK * HW + (size_t)y * W + x4;
    float4 acc = make_float4(0.f, 0.f, 0.f, 0.f);
#pragma unroll
    for (int k = 0; k < KK; k++) {
        float4 f = *reinterpret_cast<const float4*>(fb + (size_t)k * HW);
        acc.x += s[k] * f.x;
        acc.y += s[k + 1] * f.y;
        acc.z += s[k + 2] * f.z;
        acc.w += s[k + 3] * f.w;
    }
    *reinterpret_cast<float4*>(out1 + (((size_t)n * C + c) * H + y) * W + x4) = acc;

    float ss = acc.x * acc.x + acc.y * acc.y + acc.z * acc.z + acc.w * acc.w;
#pragma unroll
    for (int off = 32; off; off >>= 1) ss += __shfl_down(ss, off);
    __shared__ float wred[4];
    if ((t & 63) == 0) wred[t >> 6] = ss;
    __syncthreads();
    if (t == 0) part[bid] = wred[0] + wred[1] + wred[2] + wred[3];
}

// ---------------- vertical strip conv (float4 sliding window, TY=16) + affine ----------------
__global__ __launch_bounds__(256) void convv_kernel(const float* __restrict__ out1,
                                                    const float* __restrict__ filt,
                                                    const float* __restrict__ x,
                                                    const float* __restrict__ gamma,
                                                    const float* __restrict__ beta,
                                                    float* __restrict__ out) {
    int bid = blockIdx.x;
    int yc = bid & 3;
    int c = (bid >> 2) & (C - 1);
    int n = bid >> 8;
    int g = c >> 5;
    int t = threadIdx.x;
    int x4 = (t & 63) * 4;
    int ys = yc * 64 + (t >> 6) * 16;

    const float* plane = out1 + ((size_t)n * C + c) * HW;
    float4 win[KK];
#pragma unroll
    for (int i = 0; i < 4; i++) {
        int yy = ys - 2 + i;
        yy = yy < 0 ? -yy : yy;
        win[i] = *reinterpret_cast<const float4*>(plane + (size_t)yy * W + x4);
    }
    float gm = gamma[c], bt = beta[c];
    const float* fgb = filt + (size_t)g * KK * HW;
    for (int dy = 0; dy < 16; dy++) {
        int y = ys + dy;
        int yy = y + 2;
        yy = (yy >= H) ? (2 * H - 2 - yy) : yy;
        win[4] = *reinterpret_cast<const float4*>(plane + (size_t)yy * W + x4);
        const float* fb = fgb + (size_t)y * W + x4;
        float4 acc = make_float4(0.f, 0.f, 0.f, 0.f);
#pragma unroll
        for (int k = 0; k < KK; k++) {
            float4 f = *reinterpret_cast<const float4*>(fb + (size_t)k * HW);
            acc.x += win[k].x * f.x;
            acc.y += win[k].y * f.y;
            acc.z += win[k].z * f.z;
            acc.w += win[k].w * f.w;
        }
        size_t idx = (((size_t)n * C + c) * H + y) * W + x4;
        float4 xv = *reinterpret_cast<const float4*>(x + idx);
        float4 o;
        o.x = gm * acc.x + bt * xv.x;
        o.y = gm * acc.y + bt * xv.y;
        o.z = gm * acc.z + bt * xv.z;
        o.w = gm * acc.w + bt * xv.w;
        *reinterpret_cast<float4*>(out + idx) = o;
#pragma unroll
        for (int k = 0; k < 4; k++) win[k] = win[k + 1];
    }
}

extern "C" void kernel_launch(void* const* d_in, const int* in_sizes, int n_in,
                              void* d_out, int out_size, void* d_ws, size_t ws_size,
                              hipStream_t stream) {
    const float* x      = (const float*)d_in[0];
    const float* conv_h = (const float*)d_in[1];
    const float* conv_w = (const float*)d_in[2];
    const float* rv_h   = (const float*)d_in[3];
    const float* rv_w   = (const float*)d_in[4];
    const float* gamma  = (const float*)d_in[5];
    const float* beta   = (const float*)d_in[6];
    float* out = (float*)d_out;

    char* w = (char*)d_ws;
    size_t off = 0;
    float* out1   = (float*)(w + off); off += (size_t)NB * C * HW * 4;
    float* filtU  = (float*)(w + off); off += (size_t)HW * 12 * 4;
    float* filt   = (float*)(w + off); off += (size_t)NH * HW * 4;
    int*   dec    = (int*)  (w + off); off += (size_t)HW * 4;
    int*   hist   = (int*)  (w + off); off += (size_t)NBINS * NCHUNK * 4;
    int*   bintot = (int*)  (w + off); off += 4096;
    float* part1  = (float*)(w + off); off += (size_t)NB * 256 * 4;
    float* part2  = (float*)(w + off); off += (size_t)NB * 4096 * 4;

    // ---------------- pass 1: horizontal ----------------
    sumsq_kernel<<<NB * 256, 256, 0, stream>>>(x, part1);
    hash_kernel<<<NCHUNK, 256, 0, stream>>>(x, part1, 256, rv_h, conv_h, filtU, dec, hist);
    scan1_kernel<<<NBINS / 4, 256, 0, stream>>>(hist, bintot);
    scatter_kernel<<<NCHUNK, 256, 0, stream>>>(dec, hist, bintot, filtU, filt);
    convh_kernel<<<NB * C * (H / 4), 256, 0, stream>>>(x, filt, out1, part2);

    // ---------------- pass 2: vertical + affine ----------------
    hash_kernel<<<NCHUNK, 256, 0, stream>>>(out1, part2, 4096, rv_w, conv_w, filtU, dec, hist);
    scan1_kernel<<<NBINS / 4, 256, 0, stream>>>(hist, bintot);
    scatter_kernel<<<NCHUNK, 256, 0, stream>>>(dec, hist, bintot, filtU, filt);
    convv_kernel<<<NB * C * 4, 256, 0, stream>>>(out1, filt, x, gamma, beta, out);
}